// Round 8
// baseline (123.515 us; speedup 1.0000x reference)
//
#include <hip/hip_runtime.h>
#include <math.h>

#define B_ 4
#define L_ 2048
#define D_ 216
#define H_ 4
#define HD 54
#define HDP 64
#define M_ 64
#define LK 2112
#define NT_ 33      // LK/64 col-tiles
#define KP 256      // padded K for MFMA GEMMs
#define QT_ 16      // q-tiles per (b,h), 128 rows each
#define SPB 44      // split-blocks per (b,h): sum ceil((2qt+3)/8)
#define QSCALE 0.19632593f   // 54^-0.5 * log2(e)

typedef __attribute__((ext_vector_type(8))) __bf16 bf16x8;
typedef __attribute__((ext_vector_type(4))) __bf16 bf16x4;
typedef __attribute__((ext_vector_type(4))) float f32x4;

// packed q/k column -> original d: pc j (0..53) = 2*ii+half -> ii + 27*half
__device__ __forceinline__ int unpack_d(int j) { return (j >> 1) + 27 * (j & 1); }

// ---------------------------------------------------------------------------
// prep: wqkvt (pair-permuted) | wot | sincos table | bias | flags | memkv
// ---------------------------------------------------------------------------
__global__ __launch_bounds__(256) void prep(const float* __restrict__ Wqkv,
                                            const float* __restrict__ Wo,
                                            const int* __restrict__ amask,
                                            const float* __restrict__ mk,
                                            const float* __restrict__ mv,
                                            __bf16* __restrict__ wqkvt,
                                            __bf16* __restrict__ wot,
                                            float2* __restrict__ table,
                                            float* __restrict__ bias,
                                            int* __restrict__ padflag,
                                            __bf16* __restrict__ kall,
                                            __bf16* __restrict__ vt) {
    const int bid = blockIdx.x, tid = threadIdx.x;
    if (bid < 768) {                       // wqkvt [768][256], packed columns
        int idx = bid * 256 + tid;
        int pc = idx >> 8, k = idx & 255;
        float v = 0.f;
        if (k < 216) {
            int col = -1;
            if (pc < 256) { int h = pc >> 6, j = pc & 63;
                if (j < HD) col = h * HD + unpack_d(j); }
            else if (pc < 512) { int h = (pc - 256) >> 6, j = (pc - 256) & 63;
                if (j < HD) col = 216 + h * HD + unpack_d(j); }
            else if (pc < 728) col = 432 + (pc - 512);
            if (col >= 0) v = Wqkv[(size_t)k * 648 + col];
        }
        wqkvt[idx] = (__bf16)v;
    } else if (bid < 1024) {               // wot [256][256]
        int idx = (bid - 768) * 256 + tid;
        int n = idx >> 8, k = idx & 255;
        wot[idx] = (__bf16)((n < 216 && k < 216) ? Wo[(size_t)k * 216 + n] : 0.f);
    } else if (bid < 1280) {               // sincos table [2048][32] float2
        int idx = (bid - 1024) * 256 + tid;
        int l = idx >> 5, ii = idx & 31;
        float2 sc = {0.f, 0.f};
        if (ii < 27) {
            float ang = (float)l * exp2f(-0.49213749924f * (float)ii);
            sc.x = sinf(ang); sc.y = cosf(ang);
        }
        table[idx] = sc;
    } else if (bid < 1313) {               // bias [B][LK]
        int idx = (bid - 1280) * 256 + tid;
        if (idx < B_ * LK) {
            int b = idx / LK, c = idx % LK;
            bias[idx] = (c < M_ || amask[b * L_ + c - M_] != 0) ? 0.f : -1e30f;
        }
    } else if (bid == 1313) {              // pad_flags [B][33]
        if (tid < B_ * NT_) {
            int b = tid / NT_, tile = tid % NT_;
            int flag = 0;
            for (int u = 0; u < 64; ++u) {
                int c = tile * 64 + u;
                if (c >= M_ && c < LK && amask[b * L_ + c - M_] == 0) flag = 1;
            }
            padflag[tid] = flag;
        }
    } else {                               // memkv (packed-d for K, natural for V)
        int idx = (bid - 1314) * 256 + tid;   // 65536
        int b  = idx >> 14;
        int m  = (idx >> 8) & 63;
        int h  = (idx >> 6) & 3;
        int dd = idx & 63;
        float kv = (dd < HD) ? mk[((size_t)(b * M_ + m)) * D_ + h * HD + unpack_d(dd)] : 0.f;
        kall[((size_t)(b * 4 + h) * LK + m) * HDP + dd] = (__bf16)kv;
        if (dd < HD)
            vt[((size_t)(b * 4 + h) * HD + dd) * LK + m] =
                (__bf16)mv[((size_t)(b * M_ + m)) * D_ + h * HD + dd];
    }
}

// ---------------------------------------------------------------------------
// Fused QKV GEMM + RoPE epilogue (R7-verified).
// ---------------------------------------------------------------------------
__global__ __launch_bounds__(256) void gemm_qkv(const float* __restrict__ x,
                                                const __bf16* __restrict__ Bt,
                                                const float2* __restrict__ table,
                                                __bf16* __restrict__ qb,
                                                __bf16* __restrict__ kall,
                                                __bf16* __restrict__ vt) {
    __shared__ __align__(16) __bf16 As[8192];   // [128][64] swizzled
    __shared__ __align__(16) __bf16 Bs[4096];   // [64][64] swizzled
    const int col0 = blockIdx.x * 64;
    const int row0 = blockIdx.y * 128;
    const int tid = threadIdx.x;
    const int lane = tid & 63;
    const int w = tid >> 6, wm = w >> 1, wn = w & 1;
    const int l15 = lane & 15, l4 = lane >> 4;

    f32x4 acc[4][2];
    #pragma unroll
    for (int m = 0; m < 4; ++m)
        #pragma unroll
        for (int n = 0; n < 2; ++n) acc[m][n] = (f32x4){0.f, 0.f, 0.f, 0.f};

    float4 rfa[4][2];
    bf16x8 rb[2];
    #pragma unroll
    for (int i = 0; i < 4; ++i) { int c = tid + 256 * i, r = c >> 3, c8 = c & 7;
        int k = c8 * 8;
        rfa[i][0] = *reinterpret_cast<const float4*>(x + (size_t)(row0 + r) * 216 + k);
        rfa[i][1] = *reinterpret_cast<const float4*>(x + (size_t)(row0 + r) * 216 + k + 4); }
    #pragma unroll
    for (int i = 0; i < 2; ++i) { int c = tid + 256 * i, r = c >> 3, c8 = c & 7;
        rb[i] = *reinterpret_cast<const bf16x8*>(Bt + (size_t)(col0 + r) * KP + c8 * 8); }

    for (int kit = 0; kit < 4; ++kit) {
        __syncthreads();
        #pragma unroll
        for (int i = 0; i < 4; ++i) { int c = tid + 256 * i, r = c >> 3, c8 = c & 7;
            bf16x8 v;
            #pragma unroll
            for (int j = 0; j < 4; ++j) { v[j] = (__bf16)rfa[i][0][j]; v[4 + j] = (__bf16)rfa[i][1][j]; }
            *reinterpret_cast<bf16x8*>(&As[r * 64 + ((c8 ^ (r & 7)) * 8)]) = v; }
        #pragma unroll
        for (int i = 0; i < 2; ++i) { int c = tid + 256 * i, r = c >> 3, c8 = c & 7;
            *reinterpret_cast<bf16x8*>(&Bs[r * 64 + ((c8 ^ (r & 7)) * 8)]) = rb[i]; }
        __syncthreads();
        if (kit < 3) {
            const int k0 = (kit + 1) * 64;
            #pragma unroll
            for (int i = 0; i < 4; ++i) { int c = tid + 256 * i, r = c >> 3, c8 = c & 7;
                int k = k0 + c8 * 8;
                if (k < 216) {
                    rfa[i][0] = *reinterpret_cast<const float4*>(x + (size_t)(row0 + r) * 216 + k);
                    rfa[i][1] = *reinterpret_cast<const float4*>(x + (size_t)(row0 + r) * 216 + k + 4);
                } else {
                    rfa[i][0] = (float4){0.f, 0.f, 0.f, 0.f};
                    rfa[i][1] = (float4){0.f, 0.f, 0.f, 0.f};
                } }
            #pragma unroll
            for (int i = 0; i < 2; ++i) { int c = tid + 256 * i, r = c >> 3, c8 = c & 7;
                rb[i] = *reinterpret_cast<const bf16x8*>(Bt + (size_t)(col0 + r) * KP + k0 + c8 * 8); }
        }
        #pragma unroll
        for (int ks = 0; ks < 2; ++ks) {
            bf16x8 af[4], bfr[2];
            #pragma unroll
            for (int m = 0; m < 4; ++m) { int row = wm * 64 + m * 16 + l15; int ch = ks * 4 + l4;
                af[m] = *reinterpret_cast<const bf16x8*>(&As[row * 64 + ((ch ^ (row & 7)) * 8)]); }
            #pragma unroll
            for (int n = 0; n < 2; ++n) { int row = wn * 32 + n * 16 + l15; int ch = ks * 4 + l4;
                bfr[n] = *reinterpret_cast<const bf16x8*>(&Bs[row * 64 + ((ch ^ (row & 7)) * 8)]); }
            #pragma unroll
            for (int m = 0; m < 4; ++m)
                #pragma unroll
                for (int n = 0; n < 2; ++n)
                    acc[m][n] = __builtin_amdgcn_mfma_f32_16x16x32_bf16(af[m], bfr[n], acc[m][n], 0, 0, 0);
        }
    }

    // ---- fused RoPE epilogue ----
    #pragma unroll
    for (int m = 0; m < 4; ++m)
        #pragma unroll
        for (int n = 0; n < 2; ++n) {
            const int cc = col0 + wn * 32 + n * 16 + l15;
            const int rowb = row0 + wm * 64 + m * 16 + l4 * 4;
            const int b = rowb >> 11;
            const int lbase = rowb & 2047;
            if (cc < 512) {                     // q (cc<256) or k region, packed
                const bool isq = cc < 256;
                const int h = (cc >> 6) & 3, j = cc & 63;
                const int half = j & 1, ii = j >> 1;   // table padded to 32
                #pragma unroll
                for (int rr = 0; rr < 4; ++rr) {
                    float me = acc[m][n][rr];
                    float pr = __shfl_xor(me, 1);
                    float2 sc = table[(lbase + rr) * 32 + ii];
                    float v = me * sc.y + (half ? pr * sc.x : -pr * sc.x);
                    if (isq) {
                        qb[((size_t)(b * 4 + h) * L_ + lbase + rr) * HDP + j] =
                            (__bf16)(v * QSCALE);
                    } else {
                        kall[((size_t)(b * 4 + h) * LK + M_ + lbase + rr) * HDP + j] =
                            (__bf16)v;
                    }
                }
            } else if (cc < 728) {              // v region, natural order, transpose
                const int dp = cc - 512;
                const int h = (dp * 1214) >> 16;     // dp/54
                const int d = dp - h * 54;
                #pragma unroll
                for (int rr = 0; rr < 4; ++rr)
                    vt[((size_t)(b * 4 + h) * HD + d) * LK + M_ + lbase + rr] =
                        (__bf16)acc[m][n][rr];
            }
        }
}

// ---------------------------------------------------------------------------
// bf16 MFMA GEMM (R4-verified): C[8192][N] fp32 = A[8192][256] @ Bt[256][256]^T
// ---------------------------------------------------------------------------
__global__ __launch_bounds__(256) void gemm_out(const __bf16* __restrict__ A,
                                                const __bf16* __restrict__ Bt,
                                                float* __restrict__ C, int N) {
    __shared__ __align__(16) __bf16 As[8192];
    __shared__ __align__(16) __bf16 Bs[4096];
    const int col0 = blockIdx.x * 64;
    const int row0 = blockIdx.y * 128;
    const int tid = threadIdx.x;
    const int lane = tid & 63;
    const int w = tid >> 6, wm = w >> 1, wn = w & 1;
    const int l15 = lane & 15, l4 = lane >> 4;

    f32x4 acc[4][2];
    #pragma unroll
    for (int m = 0; m < 4; ++m)
        #pragma unroll
        for (int n = 0; n < 2; ++n) acc[m][n] = (f32x4){0.f, 0.f, 0.f, 0.f};

    bf16x8 ra[4], rb[2];
    #pragma unroll
    for (int i = 0; i < 4; ++i) { int c = tid + 256 * i, r = c >> 3, c8 = c & 7;
        ra[i] = *reinterpret_cast<const bf16x8*>(A + (size_t)(row0 + r) * KP + c8 * 8); }
    #pragma unroll
    for (int i = 0; i < 2; ++i) { int c = tid + 256 * i, r = c >> 3, c8 = c & 7;
        rb[i] = *reinterpret_cast<const bf16x8*>(Bt + (size_t)(col0 + r) * KP + c8 * 8); }

    for (int kit = 0; kit < 4; ++kit) {
        __syncthreads();
        #pragma unroll
        for (int i = 0; i < 4; ++i) { int c = tid + 256 * i, r = c >> 3, c8 = c & 7;
            *reinterpret_cast<bf16x8*>(&As[r * 64 + ((c8 ^ (r & 7)) * 8)]) = ra[i]; }
        #pragma unroll
        for (int i = 0; i < 2; ++i) { int c = tid + 256 * i, r = c >> 3, c8 = c & 7;
            *reinterpret_cast<bf16x8*>(&Bs[r * 64 + ((c8 ^ (r & 7)) * 8)]) = rb[i]; }
        __syncthreads();
        if (kit < 3) {
            const int k0 = (kit + 1) * 64;
            #pragma unroll
            for (int i = 0; i < 4; ++i) { int c = tid + 256 * i, r = c >> 3, c8 = c & 7;
                ra[i] = *reinterpret_cast<const bf16x8*>(A + (size_t)(row0 + r) * KP + k0 + c8 * 8); }
            #pragma unroll
            for (int i = 0; i < 2; ++i) { int c = tid + 256 * i, r = c >> 3, c8 = c & 7;
                rb[i] = *reinterpret_cast<const bf16x8*>(Bt + (size_t)(col0 + r) * KP + k0 + c8 * 8); }
        }
        #pragma unroll
        for (int ks = 0; ks < 2; ++ks) {
            bf16x8 af[4], bfr[2];
            #pragma unroll
            for (int m = 0; m < 4; ++m) { int row = wm * 64 + m * 16 + l15; int ch = ks * 4 + l4;
                af[m] = *reinterpret_cast<const bf16x8*>(&As[row * 64 + ((ch ^ (row & 7)) * 8)]); }
            #pragma unroll
            for (int n = 0; n < 2; ++n) { int row = wn * 32 + n * 16 + l15; int ch = ks * 4 + l4;
                bfr[n] = *reinterpret_cast<const bf16x8*>(&Bs[row * 64 + ((ch ^ (row & 7)) * 8)]); }
            #pragma unroll
            for (int m = 0; m < 4; ++m)
                #pragma unroll
                for (int n = 0; n < 2; ++n)
                    acc[m][n] = __builtin_amdgcn_mfma_f32_16x16x32_bf16(af[m], bfr[n], acc[m][n], 0, 0, 0);
        }
    }
    #pragma unroll
    for (int m = 0; m < 4; ++m)
        #pragma unroll
        for (int n = 0; n < 2; ++n) {
            int cc = col0 + wn * 32 + n * 16 + l15;
            if (cc < N) {
                #pragma unroll
                for (int rr = 0; rr < 4; ++rr)
                    C[(size_t)(row0 + wm * 64 + m * 16 + l4 * 4 + rr) * N + cc] = acc[m][n][rr];
            }
        }
}

// ---------------------------------------------------------------------------
// flash split-K, QBLK=128: block = (split, b*H+h); q-tile = 128 rows; each
// wave owns 32 q-rows as 2 row-groups (g). K/V frags reused across groups.
// Partials: op[pb][54][128] fp32, ml[pb][128][2].
// ---------------------------------------------------------------------------
__global__ __launch_bounds__(256) void flash_split(const __bf16* __restrict__ qb,
                                                   const __bf16* __restrict__ kall,
                                                   const __bf16* __restrict__ vt,
                                                   const float* __restrict__ bias,
                                                   const int* __restrict__ padflag,
                                                   float* __restrict__ op,
                                                   float* __restrict__ ml) {
    int qt = QT_ - 1, sp = 0;
    {
        int sidx = blockIdx.x, accq = 0;
        for (int q = 0; q < QT_; ++q) {
            int c = (2 * q + 10) >> 3;   // ceil((2q+3)/8)
            if (sidx < accq + c) { qt = q; sp = sidx - accq; break; }
            accq += c;
        }
    }
    const int pb = blockIdx.y * SPB + blockIdx.x;
    const int q0 = qt * 128;
    const int bh = blockIdx.y;
    const int b = bh >> 2;
    const int ktiles = 2 * qt + 3;
    const int tstart = sp * 8;
    const int tend = min(tstart + 8, ktiles);

    __shared__ __align__(16) __bf16 Qs[8192];   // [128][64] swizzled
    __shared__ __align__(16) __bf16 Ks[4096];
    __shared__ __align__(16) __bf16 Vs[4096];
    __shared__ __align__(16) __bf16 Ps[8192];   // [128][64] swizzled
    __shared__ float biasS[64];

    const int tid = threadIdx.x;
    const int lane = tid & 63;
    const int w = tid >> 6;
    const int l15 = lane & 15;
    const int l4 = lane >> 4;

    {   // stage Q (swizzled, 128 rows) + zero V pad rows
        const __bf16* src = qb + ((size_t)bh * L_ + q0) * HDP;
        for (int ch = tid; ch < 1024; ch += 256) {
            int row = ch >> 3, c8 = ch & 7;
            bf16x8 v = *reinterpret_cast<const bf16x8*>(src + ch * 8);
            *reinterpret_cast<bf16x8*>(&Qs[row * 64 + ((c8 ^ (row & 7)) * 8)]) = v;
        }
        if (tid < 80) {
            int d = 54 + (tid >> 3), c8 = tid & 7;
            bf16x8 z{};
            *reinterpret_cast<bf16x8*>(&Vs[d * 64 + ((c8 ^ (d & 7)) * 8)]) = z;
        }
    }

    const __bf16* kbase = kall + (size_t)bh * LK * HDP;
    const __bf16* vbase = vt + (size_t)bh * HD * LK;

    // prefetch first tile
    bf16x8 rk[2], rv[2];
    float biasR = 0.f;
    int flagC;
    {
        const __bf16* ks = kbase + (size_t)tstart * 64 * HDP;
        rk[0] = *reinterpret_cast<const bf16x8*>(ks + tid * 8);
        rk[1] = *reinterpret_cast<const bf16x8*>(ks + (tid + 256) * 8);
        { int d = tid >> 3, c8 = tid & 7;
          rv[0] = *reinterpret_cast<const bf16x8*>(vbase + (size_t)d * LK + tstart * 64 + c8 * 8); }
        if (tid < 176) { int c = tid + 256, d = c >> 3, c8 = c & 7;
          rv[1] = *reinterpret_cast<const bf16x8*>(vbase + (size_t)d * LK + tstart * 64 + c8 * 8); }
        if (tid < 64) biasR = bias[b * LK + tstart * 64 + tid];
        flagC = padflag[b * NT_ + tstart];
    }

    __syncthreads();
    bf16x8 aQ[2][2];
    #pragma unroll
    for (int g = 0; g < 2; ++g) {
        int qrow = 32 * w + 16 * g + l15, s = (qrow & 7) << 3;
        aQ[g][0] = *reinterpret_cast<const bf16x8*>(&Qs[qrow * 64 + ((l4 * 8) ^ s)]);
        aQ[g][1] = *reinterpret_cast<const bf16x8*>(&Qs[qrow * 64 + ((32 + l4 * 8) ^ s)]);
    }

    f32x4 Oacc[2][4];
    float m_run[2], l_run[2];
    #pragma unroll
    for (int g = 0; g < 2; ++g) {
        m_run[g] = -1e30f; l_run[g] = 0.f;
        #pragma unroll
        for (int nt = 0; nt < 4; ++nt) Oacc[g][nt] = (f32x4){0.f, 0.f, 0.f, 0.f};
    }

    for (int t = tstart; t < tend; ++t) {
        const int cbase = t * 64;
        __syncthreads();
        { int r = tid >> 3, c8 = tid & 7;
          *reinterpret_cast<bf16x8*>(&Ks[r * 64 + ((c8 ^ (r & 7)) * 8)]) = rk[0]; }
        { int c = tid + 256, r = c >> 3, c8 = c & 7;
          *reinterpret_cast<bf16x8*>(&Ks[r * 64 + ((c8 ^ (r & 7)) * 8)]) = rk[1]; }
        { int d = tid >> 3, c8 = tid & 7;
          *reinterpret_cast<bf16x8*>(&Vs[d * 64 + ((c8 ^ (d & 7)) * 8)]) = rv[0]; }
        if (tid < 176) { int c = tid + 256, d = c >> 3, c8 = c & 7;
          *reinterpret_cast<bf16x8*>(&Vs[d * 64 + ((c8 ^ (d & 7)) * 8)]) = rv[1]; }
        if (tid < 64) biasS[tid] = biasR;
        const int flag = flagC;
        __syncthreads();
        if (t + 1 < tend) {
            const __bf16* ks = kbase + (size_t)(cbase + 64) * HDP;
            rk[0] = *reinterpret_cast<const bf16x8*>(ks + tid * 8);
            rk[1] = *reinterpret_cast<const bf16x8*>(ks + (tid + 256) * 8);
            { int d = tid >> 3, c8 = tid & 7;
              rv[0] = *reinterpret_cast<const bf16x8*>(vbase + (size_t)d * LK + cbase + 64 + c8 * 8); }
            if (tid < 176) { int c = tid + 256, d = c >> 3, c8 = c & 7;
              rv[1] = *reinterpret_cast<const bf16x8*>(vbase + (size_t)d * LK + cbase + 64 + c8 * 8); }
            if (tid < 64) biasR = bias[b * LK + cbase + 64 + tid];
            flagC = padflag[b * NT_ + t + 1];
        }

        // S^T = K Q^T, both row-groups share K fragments
        f32x4 S[2][4];
        #pragma unroll
        for (int nt = 0; nt < 4; ++nt) {
            int krow = nt * 16 + l15, s = (krow & 7) << 3;
            bf16x8 b0 = *reinterpret_cast<const bf16x8*>(&Ks[krow * 64 + ((l4 * 8) ^ s)]);
            bf16x8 b1 = *reinterpret_cast<const bf16x8*>(&Ks[krow * 64 + ((32 + l4 * 8) ^ s)]);
            #pragma unroll
            for (int g = 0; g < 2; ++g) {
                f32x4 acc = (f32x4){0.f, 0.f, 0.f, 0.f};
                acc = __builtin_amdgcn_mfma_f32_16x16x32_bf16(b0, aQ[g][0], acc, 0, 0, 0);
                acc = __builtin_amdgcn_mfma_f32_16x16x32_bf16(b1, aQ[g][1], acc, 0, 0, 0);
                S[g][nt] = acc;
            }
        }
        if (flag) {
            #pragma unroll
            for (int g = 0; g < 2; ++g)
                #pragma unroll
                for (int nt = 0; nt < 4; ++nt)
                    #pragma unroll
                    for (int r = 0; r < 4; ++r)
                        S[g][nt][r] += biasS[nt * 16 + l4 * 4 + r];
        }
        if (t >= 2 * qt + 1) {   // diagonal band: last two tiles
            #pragma unroll
            for (int g = 0; g < 2; ++g) {
                int rq = q0 + 32 * w + 16 * g + l15;
                #pragma unroll
                for (int nt = 0; nt < 4; ++nt)
                    #pragma unroll
                    for (int r = 0; r < 4; ++r) {
                        int cg = cbase + nt * 16 + l4 * 4 + r;
                        if (cg > rq + M_) S[g][nt][r] = -1e30f;
                    }
            }
        }
        // softmax per row-group
        float alpha[2];
        #pragma unroll
        for (int g = 0; g < 2; ++g) {
            float mx = fmaxf(fmaxf(S[g][0][0], S[g][0][1]), fmaxf(S[g][0][2], S[g][0][3]));
            #pragma unroll
            for (int nt = 1; nt < 4; ++nt)
                mx = fmaxf(mx, fmaxf(fmaxf(S[g][nt][0], S[g][nt][1]),
                                     fmaxf(S[g][nt][2], S[g][nt][3])));
            mx = fmaxf(mx, __shfl_xor(mx, 16));
            mx = fmaxf(mx, __shfl_xor(mx, 32));
            float m_new = fmaxf(m_run[g], mx);
            alpha[g] = exp2f(m_run[g] - m_new);
            m_run[g] = m_new;
            float ls = 0.f;
            #pragma unroll
            for (int nt = 0; nt < 4; ++nt)
                #pragma unroll
                for (int r = 0; r < 4; ++r) {
                    float pv = exp2f(S[g][nt][r] - m_new);
                    S[g][nt][r] = pv;
                    ls += pv;
                }
            ls += __shfl_xor(ls, 16);
            ls += __shfl_xor(ls, 32);
            l_run[g] = l_run[g] * alpha[g] + ls;
            // P -> Ps (wave-private rows), packed b64 stores
            int prow = 32 * w + 16 * g + l15, s = (prow & 7) << 3;
            #pragma unroll
            for (int nt = 0; nt < 4; ++nt) {
                bf16x4 pk;
                pk[0] = (__bf16)S[g][nt][0]; pk[1] = (__bf16)S[g][nt][1];
                pk[2] = (__bf16)S[g][nt][2]; pk[3] = (__bf16)S[g][nt][3];
                *reinterpret_cast<bf16x4*>(&Ps[prow * 64 + ((nt * 16 + l4 * 4) ^ s)]) = pk;
            }
        }
        // alpha to O-row space, rescale
        #pragma unroll
        for (int g = 0; g < 2; ++g) {
            float aO[4];
            #pragma unroll
            for (int r = 0; r < 4; ++r)
                aO[r] = __shfl(alpha[g], (lane & 0x30) | (l4 * 4 + r), 64);
            #pragma unroll
            for (int nt = 0; nt < 4; ++nt)
                #pragma unroll
                for (int r = 0; r < 4; ++r) Oacc[g][nt][r] *= aO[r];
        }
        // PV: V fragments shared across row-groups
        bf16x8 aP[2][2];
        #pragma unroll
        for (int g = 0; g < 2; ++g) {
            int prow = 32 * w + 16 * g + l15, s = (prow & 7) << 3;
            aP[g][0] = *reinterpret_cast<const bf16x8*>(&Ps[prow * 64 + ((l4 * 8) ^ s)]);
            aP[g][1] = *reinterpret_cast<const bf16x8*>(&Ps[prow * 64 + ((32 + l4 * 8) ^ s)]);
        }
        #pragma unroll
        for (int nt = 0; nt < 4; ++nt) {
            int vrow = nt * 16 + l15, s = (vrow & 7) << 3;
            bf16x8 v0 = *reinterpret_cast<const bf16x8*>(&Vs[vrow * 64 + ((l4 * 8) ^ s)]);
            bf16x8 v1 = *reinterpret_cast<const bf16x8*>(&Vs[vrow * 64 + ((32 + l4 * 8) ^ s)]);
            #pragma unroll
            for (int g = 0; g < 2; ++g) {
                Oacc[g][nt] = __builtin_amdgcn_mfma_f32_16x16x32_bf16(aP[g][0], v0, Oacc[g][nt], 0, 0, 0);
                Oacc[g][nt] = __builtin_amdgcn_mfma_f32_16x16x32_bf16(aP[g][1], v1, Oacc[g][nt], 0, 0, 0);
            }
        }
    }

    // emit partials (unnormalized)
    if (l4 == 0) {
        #pragma unroll
        for (int g = 0; g < 2; ++g) {
            int row = 32 * w + 16 * g + l15;
            ml[((size_t)pb * 128 + row) * 2 + 0] = m_run[g];
            ml[((size_t)pb * 128 + row) * 2 + 1] = l_run[g];
        }
    }
    #pragma unroll
    for (int g = 0; g < 2; ++g)
        #pragma unroll
        for (int nt = 0; nt < 4; ++nt) {
            int c = nt * 16 + l15;
            if (c < HD) {
                #pragma unroll
                for (int r = 0; r < 4; ++r)
                    op[((size_t)pb * HD + c) * 128 + 32 * w + 16 * g + l4 * 4 + r] =
                        Oacc[g][nt][r];
            }
        }
}

// ---------------------------------------------------------------------------
// combine partials -> aoutb bf16 [8192][256].  row = tid&127, dseg = tid>>7.
// ---------------------------------------------------------------------------
__global__ __launch_bounds__(256) void combine(const float* __restrict__ op,
                                               const float* __restrict__ ml,
                                               __bf16* __restrict__ aoutb) {
    const int qt = blockIdx.x, bh = blockIdx.y;
    const int b = bh >> 2, h = bh & 3;
    const int ns = (2 * qt + 10) >> 3;   // ceil((2qt+3)/8), <=5
    int accq = 0;
    for (int q = 0; q < qt; ++q) accq += (2 * q + 10) >> 3;
    const int pb0 = bh * SPB + accq;
    const int row = threadIdx.x & 127;
    const int dseg = threadIdx.x >> 7;   // 0..1, owns d = dseg*27 .. +26

    float mi[5], li[5];
    float m = -1e30f;
    for (int i = 0; i < ns; ++i) {
        mi[i] = ml[((size_t)(pb0 + i) * 128 + row) * 2 + 0];
        li[i] = ml[((size_t)(pb0 + i) * 128 + row) * 2 + 1];
        m = fmaxf(m, mi[i]);
    }
    float wgt[5], Lr = 0.f;
    for (int i = 0; i < ns; ++i) {
        wgt[i] = exp2f(mi[i] - m);
        Lr += li[i] * wgt[i];
    }
    float inv = 1.f / Lr;
    #pragma unroll
    for (int j = 0; j < 27; ++j) {
        int d = dseg * 27 + j;
        float o = 0.f;
        for (int i = 0; i < ns; ++i)
            o += wgt[i] * op[((size_t)(pb0 + i) * HD + d) * 128 + row];
        aoutb[((size_t)(b * L_) + qt * 128 + row) * KP + h * HD + d] = (__bf16)(o * inv);
    }
}

// ---------------------------------------------------------------------------
extern "C" void kernel_launch(void* const* d_in, const int* in_sizes, int n_in,
                              void* d_out, int out_size, void* d_ws, size_t ws_size,
                              hipStream_t stream) {
    const float* x     = (const float*)d_in[0];
    const float* mem_k = (const float*)d_in[1];
    const float* mem_v = (const float*)d_in[2];
    const int*   amask = (const int*)d_in[3];
    const float* Wqkv  = (const float*)d_in[4];
    const float* Wo    = (const float*)d_in[5];
    float* out = (float*)d_out;

    char* p = (char*)d_ws;
    float* bias    = (float*)p;        p += (size_t)B_ * LK * 4;
    int*   padflag = (int*)p;          p += (size_t)B_ * NT_ * 4;
    float2* table  = (float2*)p;       p += (size_t)2048 * 32 * 8;
    __bf16* wqkvt  = (__bf16*)p;       p += (size_t)768 * KP * 2;
    __bf16* wot    = (__bf16*)p;       p += (size_t)256 * KP * 2;
    __bf16* aoutb  = (__bf16*)p;       p += (size_t)8192 * KP * 2;
    __bf16* qb     = (__bf16*)p;       p += (size_t)16 * 2048 * 64 * 2;
    __bf16* kall   = (__bf16*)p;       p += (size_t)16 * 2112 * 64 * 2;
    __bf16* vt     = (__bf16*)p;       p += (size_t)16 * 54 * 2112 * 2;
    float* opbuf   = (float*)p;        p += (size_t)16 * SPB * HD * 128 * 4;  // 19.5MB
    float* mlbuf   = (float*)p;        p += (size_t)16 * SPB * 128 * 2 * 4;

    prep<<<dim3(1570), 256, 0, stream>>>(Wqkv, Wo, amask, mem_k, mem_v,
                                         wqkvt, wot, table, bias, padflag, kall, vt);
    gemm_qkv<<<dim3(12, 64), 256, 0, stream>>>(x, wqkvt, table, qb, kall, vt);
    flash_split<<<dim3(SPB, 16), 256, 0, stream>>>(qb, kall, vt, bias, padflag,
                                                   opbuf, mlbuf);
    combine<<<dim3(QT_, 16), 256, 0, stream>>>(opbuf, mlbuf, aoutb);
    gemm_out<<<dim3(4, 64), 256, 0, stream>>>(aoutb, wot, out, 216);
}

// Round 9
// 100.671 us; speedup vs baseline: 1.2269x; 1.2269x over previous
//
#include <hip/hip_runtime.h>
#include <math.h>

#define B_ 4
#define L_ 2048
#define D_ 216
#define H_ 4
#define HD 54
#define HDP 64
#define M_ 64
#define LK 2112
#define NT_ 33      // LK/64 col-tiles
#define KP 256      // padded K for MFMA GEMMs
#define SPB 84      // split-blocks per (b,h): sum ceil((qt+2)/8)
#define QSCALE 0.19632593f   // 54^-0.5 * log2(e)

typedef __attribute__((ext_vector_type(8))) __bf16 bf16x8;
typedef __attribute__((ext_vector_type(4))) __bf16 bf16x4;
typedef __attribute__((ext_vector_type(4))) float f32x4;

// packed q/k column -> original d: pc j (0..53) = 2*ii+half -> ii + 27*half
__device__ __forceinline__ int unpack_d(int j) { return (j >> 1) + 27 * (j & 1); }

// ---------------------------------------------------------------------------
// prep: wqkvt (pair-permuted) | wot | sincos table | bias | flags | memkv
// ---------------------------------------------------------------------------
__global__ __launch_bounds__(256) void prep(const float* __restrict__ Wqkv,
                                            const float* __restrict__ Wo,
                                            const int* __restrict__ amask,
                                            const float* __restrict__ mk,
                                            const float* __restrict__ mv,
                                            __bf16* __restrict__ wqkvt,
                                            __bf16* __restrict__ wot,
                                            float2* __restrict__ table,
                                            float* __restrict__ bias,
                                            int* __restrict__ padflag,
                                            __bf16* __restrict__ kall,
                                            __bf16* __restrict__ vt) {
    const int bid = blockIdx.x, tid = threadIdx.x;
    if (bid < 768) {                       // wqkvt [768][256], packed columns
        int idx = bid * 256 + tid;
        int pc = idx >> 8, k = idx & 255;
        float v = 0.f;
        if (k < 216) {
            int col = -1;
            if (pc < 256) { int h = pc >> 6, j = pc & 63;
                if (j < HD) col = h * HD + unpack_d(j); }
            else if (pc < 512) { int h = (pc - 256) >> 6, j = (pc - 256) & 63;
                if (j < HD) col = 216 + h * HD + unpack_d(j); }
            else if (pc < 728) col = 432 + (pc - 512);
            if (col >= 0) v = Wqkv[(size_t)k * 648 + col];
        }
        wqkvt[idx] = (__bf16)v;
    } else if (bid < 1024) {               // wot [256][256]
        int idx = (bid - 768) * 256 + tid;
        int n = idx >> 8, k = idx & 255;
        wot[idx] = (__bf16)((n < 216 && k < 216) ? Wo[(size_t)k * 216 + n] : 0.f);
    } else if (bid < 1280) {               // sincos table [2048][32] float2
        int idx = (bid - 1024) * 256 + tid;
        int l = idx >> 5, ii = idx & 31;
        float2 sc = {0.f, 0.f};
        if (ii < 27) {
            float ang = (float)l * exp2f(-0.49213749924f * (float)ii);
            sc.x = sinf(ang); sc.y = cosf(ang);
        }
        table[idx] = sc;
    } else if (bid < 1313) {               // bias [B][LK]
        int idx = (bid - 1280) * 256 + tid;
        if (idx < B_ * LK) {
            int b = idx / LK, c = idx % LK;
            bias[idx] = (c < M_ || amask[b * L_ + c - M_] != 0) ? 0.f : -1e30f;
        }
    } else if (bid == 1313) {              // pad_flags [B][33]
        if (tid < B_ * NT_) {
            int b = tid / NT_, tile = tid % NT_;
            int flag = 0;
            for (int u = 0; u < 64; ++u) {
                int c = tile * 64 + u;
                if (c >= M_ && c < LK && amask[b * L_ + c - M_] == 0) flag = 1;
            }
            padflag[tid] = flag;
        }
    } else {                               // memkv (packed-d for K, natural for V)
        int idx = (bid - 1314) * 256 + tid;   // 65536
        int b  = idx >> 14;
        int m  = (idx >> 8) & 63;
        int h  = (idx >> 6) & 3;
        int dd = idx & 63;
        float kv = (dd < HD) ? mk[((size_t)(b * M_ + m)) * D_ + h * HD + unpack_d(dd)] : 0.f;
        kall[((size_t)(b * 4 + h) * LK + m) * HDP + dd] = (__bf16)kv;
        if (dd < HD)
            vt[((size_t)(b * 4 + h) * HD + dd) * LK + m] =
                (__bf16)mv[((size_t)(b * M_ + m)) * D_ + h * HD + dd];
    }
}

// ---------------------------------------------------------------------------
// Fused QKV GEMM + RoPE epilogue (R7-verified).
// ---------------------------------------------------------------------------
__global__ __launch_bounds__(256) void gemm_qkv(const float* __restrict__ x,
                                                const __bf16* __restrict__ Bt,
                                                const float2* __restrict__ table,
                                                __bf16* __restrict__ qb,
                                                __bf16* __restrict__ kall,
                                                __bf16* __restrict__ vt) {
    __shared__ __align__(16) __bf16 As[8192];   // [128][64] swizzled
    __shared__ __align__(16) __bf16 Bs[4096];   // [64][64] swizzled
    const int col0 = blockIdx.x * 64;
    const int row0 = blockIdx.y * 128;
    const int tid = threadIdx.x;
    const int lane = tid & 63;
    const int w = tid >> 6, wm = w >> 1, wn = w & 1;
    const int l15 = lane & 15, l4 = lane >> 4;

    f32x4 acc[4][2];
    #pragma unroll
    for (int m = 0; m < 4; ++m)
        #pragma unroll
        for (int n = 0; n < 2; ++n) acc[m][n] = (f32x4){0.f, 0.f, 0.f, 0.f};

    float4 rfa[4][2];
    bf16x8 rb[2];
    #pragma unroll
    for (int i = 0; i < 4; ++i) { int c = tid + 256 * i, r = c >> 3, c8 = c & 7;
        int k = c8 * 8;
        rfa[i][0] = *reinterpret_cast<const float4*>(x + (size_t)(row0 + r) * 216 + k);
        rfa[i][1] = *reinterpret_cast<const float4*>(x + (size_t)(row0 + r) * 216 + k + 4); }
    #pragma unroll
    for (int i = 0; i < 2; ++i) { int c = tid + 256 * i, r = c >> 3, c8 = c & 7;
        rb[i] = *reinterpret_cast<const bf16x8*>(Bt + (size_t)(col0 + r) * KP + c8 * 8); }

    for (int kit = 0; kit < 4; ++kit) {
        __syncthreads();
        #pragma unroll
        for (int i = 0; i < 4; ++i) { int c = tid + 256 * i, r = c >> 3, c8 = c & 7;
            bf16x8 v;
            #pragma unroll
            for (int j = 0; j < 4; ++j) { v[j] = (__bf16)rfa[i][0][j]; v[4 + j] = (__bf16)rfa[i][1][j]; }
            *reinterpret_cast<bf16x8*>(&As[r * 64 + ((c8 ^ (r & 7)) * 8)]) = v; }
        #pragma unroll
        for (int i = 0; i < 2; ++i) { int c = tid + 256 * i, r = c >> 3, c8 = c & 7;
            *reinterpret_cast<bf16x8*>(&Bs[r * 64 + ((c8 ^ (r & 7)) * 8)]) = rb[i]; }
        __syncthreads();
        if (kit < 3) {
            const int k0 = (kit + 1) * 64;
            #pragma unroll
            for (int i = 0; i < 4; ++i) { int c = tid + 256 * i, r = c >> 3, c8 = c & 7;
                int k = k0 + c8 * 8;
                if (k < 216) {
                    rfa[i][0] = *reinterpret_cast<const float4*>(x + (size_t)(row0 + r) * 216 + k);
                    rfa[i][1] = *reinterpret_cast<const float4*>(x + (size_t)(row0 + r) * 216 + k + 4);
                } else {
                    rfa[i][0] = (float4){0.f, 0.f, 0.f, 0.f};
                    rfa[i][1] = (float4){0.f, 0.f, 0.f, 0.f};
                } }
            #pragma unroll
            for (int i = 0; i < 2; ++i) { int c = tid + 256 * i, r = c >> 3, c8 = c & 7;
                rb[i] = *reinterpret_cast<const bf16x8*>(Bt + (size_t)(col0 + r) * KP + k0 + c8 * 8); }
        }
        #pragma unroll
        for (int ks = 0; ks < 2; ++ks) {
            bf16x8 af[4], bfr[2];
            #pragma unroll
            for (int m = 0; m < 4; ++m) { int row = wm * 64 + m * 16 + l15; int ch = ks * 4 + l4;
                af[m] = *reinterpret_cast<const bf16x8*>(&As[row * 64 + ((ch ^ (row & 7)) * 8)]); }
            #pragma unroll
            for (int n = 0; n < 2; ++n) { int row = wn * 32 + n * 16 + l15; int ch = ks * 4 + l4;
                bfr[n] = *reinterpret_cast<const bf16x8*>(&Bs[row * 64 + ((ch ^ (row & 7)) * 8)]); }
            #pragma unroll
            for (int m = 0; m < 4; ++m)
                #pragma unroll
                for (int n = 0; n < 2; ++n)
                    acc[m][n] = __builtin_amdgcn_mfma_f32_16x16x32_bf16(af[m], bfr[n], acc[m][n], 0, 0, 0);
        }
    }

    // ---- fused RoPE epilogue ----
    #pragma unroll
    for (int m = 0; m < 4; ++m)
        #pragma unroll
        for (int n = 0; n < 2; ++n) {
            const int cc = col0 + wn * 32 + n * 16 + l15;
            const int rowb = row0 + wm * 64 + m * 16 + l4 * 4;
            const int b = rowb >> 11;
            const int lbase = rowb & 2047;
            if (cc < 512) {                     // q (cc<256) or k region, packed
                const bool isq = cc < 256;
                const int h = (cc >> 6) & 3, j = cc & 63;
                const int half = j & 1, ii = j >> 1;   // table padded to 32
                #pragma unroll
                for (int rr = 0; rr < 4; ++rr) {
                    float me = acc[m][n][rr];
                    float pr = __shfl_xor(me, 1);
                    float2 sc = table[(lbase + rr) * 32 + ii];
                    float v = me * sc.y + (half ? pr * sc.x : -pr * sc.x);
                    if (isq) {
                        qb[((size_t)(b * 4 + h) * L_ + lbase + rr) * HDP + j] =
                            (__bf16)(v * QSCALE);
                    } else {
                        kall[((size_t)(b * 4 + h) * LK + M_ + lbase + rr) * HDP + j] =
                            (__bf16)v;
                    }
                }
            } else if (cc < 728) {              // v region, natural order, transpose
                const int dp = cc - 512;
                const int h = (dp * 1214) >> 16;     // dp/54
                const int d = dp - h * 54;
                #pragma unroll
                for (int rr = 0; rr < 4; ++rr)
                    vt[((size_t)(b * 4 + h) * HD + d) * LK + M_ + lbase + rr] =
                        (__bf16)acc[m][n][rr];
            }
        }
}

// ---------------------------------------------------------------------------
// bf16 MFMA GEMM (R4-verified): C[8192][N] fp32 = A[8192][256] @ Bt[256][256]^T
// ---------------------------------------------------------------------------
__global__ __launch_bounds__(256) void gemm_out(const __bf16* __restrict__ A,
                                                const __bf16* __restrict__ Bt,
                                                float* __restrict__ C, int N) {
    __shared__ __align__(16) __bf16 As[8192];
    __shared__ __align__(16) __bf16 Bs[4096];
    const int col0 = blockIdx.x * 64;
    const int row0 = blockIdx.y * 128;
    const int tid = threadIdx.x;
    const int lane = tid & 63;
    const int w = tid >> 6, wm = w >> 1, wn = w & 1;
    const int l15 = lane & 15, l4 = lane >> 4;

    f32x4 acc[4][2];
    #pragma unroll
    for (int m = 0; m < 4; ++m)
        #pragma unroll
        for (int n = 0; n < 2; ++n) acc[m][n] = (f32x4){0.f, 0.f, 0.f, 0.f};

    bf16x8 ra[4], rb[2];
    #pragma unroll
    for (int i = 0; i < 4; ++i) { int c = tid + 256 * i, r = c >> 3, c8 = c & 7;
        ra[i] = *reinterpret_cast<const bf16x8*>(A + (size_t)(row0 + r) * KP + c8 * 8); }
    #pragma unroll
    for (int i = 0; i < 2; ++i) { int c = tid + 256 * i, r = c >> 3, c8 = c & 7;
        rb[i] = *reinterpret_cast<const bf16x8*>(Bt + (size_t)(col0 + r) * KP + c8 * 8); }

    for (int kit = 0; kit < 4; ++kit) {
        __syncthreads();
        #pragma unroll
        for (int i = 0; i < 4; ++i) { int c = tid + 256 * i, r = c >> 3, c8 = c & 7;
            *reinterpret_cast<bf16x8*>(&As[r * 64 + ((c8 ^ (r & 7)) * 8)]) = ra[i]; }
        #pragma unroll
        for (int i = 0; i < 2; ++i) { int c = tid + 256 * i, r = c >> 3, c8 = c & 7;
            *reinterpret_cast<bf16x8*>(&Bs[r * 64 + ((c8 ^ (r & 7)) * 8)]) = rb[i]; }
        __syncthreads();
        if (kit < 3) {
            const int k0 = (kit + 1) * 64;
            #pragma unroll
            for (int i = 0; i < 4; ++i) { int c = tid + 256 * i, r = c >> 3, c8 = c & 7;
                ra[i] = *reinterpret_cast<const bf16x8*>(A + (size_t)(row0 + r) * KP + k0 + c8 * 8); }
            #pragma unroll
            for (int i = 0; i < 2; ++i) { int c = tid + 256 * i, r = c >> 3, c8 = c & 7;
                rb[i] = *reinterpret_cast<const bf16x8*>(Bt + (size_t)(col0 + r) * KP + k0 + c8 * 8); }
        }
        #pragma unroll
        for (int ks = 0; ks < 2; ++ks) {
            bf16x8 af[4], bfr[2];
            #pragma unroll
            for (int m = 0; m < 4; ++m) { int row = wm * 64 + m * 16 + l15; int ch = ks * 4 + l4;
                af[m] = *reinterpret_cast<const bf16x8*>(&As[row * 64 + ((ch ^ (row & 7)) * 8)]); }
            #pragma unroll
            for (int n = 0; n < 2; ++n) { int row = wn * 32 + n * 16 + l15; int ch = ks * 4 + l4;
                bfr[n] = *reinterpret_cast<const bf16x8*>(&Bs[row * 64 + ((ch ^ (row & 7)) * 8)]); }
            #pragma unroll
            for (int m = 0; m < 4; ++m)
                #pragma unroll
                for (int n = 0; n < 2; ++n)
                    acc[m][n] = __builtin_amdgcn_mfma_f32_16x16x32_bf16(af[m], bfr[n], acc[m][n], 0, 0, 0);
        }
    }
    #pragma unroll
    for (int m = 0; m < 4; ++m)
        #pragma unroll
        for (int n = 0; n < 2; ++n) {
            int cc = col0 + wn * 32 + n * 16 + l15;
            if (cc < N) {
                #pragma unroll
                for (int rr = 0; rr < 4; ++rr)
                    C[(size_t)(row0 + wm * 64 + m * 16 + l4 * 4 + rr) * N + cc] = acc[m][n][rr];
            }
        }
}

// ---------------------------------------------------------------------------
// flash split-K (R7 geometry) with double-buffered K/V/bias LDS:
// ONE barrier per iteration; tile t+1 committed to buf^1 during compute of t;
// tile t+2 global loads in flight.  op[pb][54][64] + ml[pb][64][2].
// ---------------------------------------------------------------------------
__global__ __launch_bounds__(256) void flash_split(const __bf16* __restrict__ qb,
                                                   const __bf16* __restrict__ kall,
                                                   const __bf16* __restrict__ vt,
                                                   const float* __restrict__ bias,
                                                   const int* __restrict__ padflag,
                                                   float* __restrict__ op,
                                                   float* __restrict__ ml) {
    int qt = 31, sp = 0;
    {
        int sidx = blockIdx.x, accq = 0;
        for (int q = 0; q < 32; ++q) {
            int c = (q + 9) >> 3;   // ceil((q+2)/8)
            if (sidx < accq + c) { qt = q; sp = sidx - accq; break; }
            accq += c;
        }
    }
    const int pb = blockIdx.y * SPB + blockIdx.x;
    const int q0 = qt * 64;
    const int bh = blockIdx.y;
    const int b = bh >> 2;
    const int tstart = sp * 8;
    const int tend = min(tstart + 8, qt + 2);

    __shared__ __align__(16) __bf16 Qs[4096];
    __shared__ __align__(16) __bf16 Ks[2][4096];
    __shared__ __align__(16) __bf16 Vs[2][4096];
    __shared__ __align__(16) __bf16 Ps[4096];
    __shared__ float biasS[2][64];

    const int tid = threadIdx.x;
    const int lane = tid & 63;
    const int w = tid >> 6;
    const int l15 = lane & 15;
    const int l4 = lane >> 4;

    {   // stage Q (swizzled) + zero V pad rows in BOTH buffers
        const __bf16* src = qb + ((size_t)bh * L_ + q0) * HDP;
        for (int ch = tid; ch < 512; ch += 256) {
            int row = ch >> 3, c8 = ch & 7;
            bf16x8 v = *reinterpret_cast<const bf16x8*>(src + ch * 8);
            *reinterpret_cast<bf16x8*>(&Qs[row * 64 + ((c8 ^ (row & 7)) * 8)]) = v;
        }
        if (tid < 160) {
            int buf = tid >= 80, q = tid - 80 * buf;
            int d = 54 + (q >> 3), c8 = q & 7;
            bf16x8 z{};
            *reinterpret_cast<bf16x8*>(&Vs[buf][d * 64 + ((c8 ^ (d & 7)) * 8)]) = z;
        }
    }

    const int rq = q0 + 16 * w + l15;
    const __bf16* kbase = kall + (size_t)bh * LK * HDP;
    const __bf16* vbase = vt + (size_t)bh * HD * LK;

    bf16x8 rk[2], rv[2];
    float biasR = 0.f;
    {   // tile tstart: load regs and commit straight to buf 0
        const __bf16* ks = kbase + (size_t)tstart * 64 * HDP;
        rk[0] = *reinterpret_cast<const bf16x8*>(ks + tid * 8);
        rk[1] = *reinterpret_cast<const bf16x8*>(ks + (tid + 256) * 8);
        { int d = tid >> 3, c8 = tid & 7;
          rv[0] = *reinterpret_cast<const bf16x8*>(vbase + (size_t)d * LK + tstart * 64 + c8 * 8); }
        if (tid < 176) { int c = tid + 256, d = c >> 3, c8 = c & 7;
          rv[1] = *reinterpret_cast<const bf16x8*>(vbase + (size_t)d * LK + tstart * 64 + c8 * 8); }
        if (tid < 64) biasR = bias[b * LK + tstart * 64 + tid];

        { int r = tid >> 3, c8 = tid & 7;
          *reinterpret_cast<bf16x8*>(&Ks[0][r * 64 + ((c8 ^ (r & 7)) * 8)]) = rk[0]; }
        { int c = tid + 256, r = c >> 3, c8 = c & 7;
          *reinterpret_cast<bf16x8*>(&Ks[0][r * 64 + ((c8 ^ (r & 7)) * 8)]) = rk[1]; }
        { int d = tid >> 3, c8 = tid & 7;
          *reinterpret_cast<bf16x8*>(&Vs[0][d * 64 + ((c8 ^ (d & 7)) * 8)]) = rv[0]; }
        if (tid < 176) { int c = tid + 256, d = c >> 3, c8 = c & 7;
          *reinterpret_cast<bf16x8*>(&Vs[0][d * 64 + ((c8 ^ (d & 7)) * 8)]) = rv[1]; }
        if (tid < 64) biasS[0][tid] = biasR;
    }
    if (tstart + 1 < tend) {   // prefetch tile tstart+1 into regs
        const __bf16* ks = kbase + (size_t)(tstart + 1) * 64 * HDP;
        rk[0] = *reinterpret_cast<const bf16x8*>(ks + tid * 8);
        rk[1] = *reinterpret_cast<const bf16x8*>(ks + (tid + 256) * 8);
        { int d = tid >> 3, c8 = tid & 7;
          rv[0] = *reinterpret_cast<const bf16x8*>(vbase + (size_t)d * LK + (tstart + 1) * 64 + c8 * 8); }
        if (tid < 176) { int c = tid + 256, d = c >> 3, c8 = c & 7;
          rv[1] = *reinterpret_cast<const bf16x8*>(vbase + (size_t)d * LK + (tstart + 1) * 64 + c8 * 8); }
        if (tid < 64) biasR = bias[b * LK + (tstart + 1) * 64 + tid];
    }

    __syncthreads();   // Q, buf0, V-pads all visible
    bf16x8 aQ[2];
    {
        int qrow = 16 * w + l15, s = (qrow & 7) << 3;
        aQ[0] = *reinterpret_cast<const bf16x8*>(&Qs[qrow * 64 + ((l4 * 8) ^ s)]);
        aQ[1] = *reinterpret_cast<const bf16x8*>(&Qs[qrow * 64 + ((32 + l4 * 8) ^ s)]);
    }

    f32x4 Oacc[4];
    #pragma unroll
    for (int nt = 0; nt < 4; ++nt) Oacc[nt] = (f32x4){0.f, 0.f, 0.f, 0.f};
    float m_run = -1e30f, l_run = 0.f;

    int p = 0;
    for (int t = tstart; t < tend; ++t) {
        const int cbase = t * 64;
        const int qbuf = p ^ 1;
        if (t + 1 < tend) {   // commit staged regs (tile t+1) to other buffer
            { int r = tid >> 3, c8 = tid & 7;
              *reinterpret_cast<bf16x8*>(&Ks[qbuf][r * 64 + ((c8 ^ (r & 7)) * 8)]) = rk[0]; }
            { int c = tid + 256, r = c >> 3, c8 = c & 7;
              *reinterpret_cast<bf16x8*>(&Ks[qbuf][r * 64 + ((c8 ^ (r & 7)) * 8)]) = rk[1]; }
            { int d = tid >> 3, c8 = tid & 7;
              *reinterpret_cast<bf16x8*>(&Vs[qbuf][d * 64 + ((c8 ^ (d & 7)) * 8)]) = rv[0]; }
            if (tid < 176) { int c = tid + 256, d = c >> 3, c8 = c & 7;
              *reinterpret_cast<bf16x8*>(&Vs[qbuf][d * 64 + ((c8 ^ (d & 7)) * 8)]) = rv[1]; }
            if (tid < 64) biasS[qbuf][tid] = biasR;
        }
        if (t + 2 < tend) {   // issue tile t+2 global loads (in flight over compute)
            const __bf16* ks = kbase + (size_t)(cbase + 128) * HDP;
            rk[0] = *reinterpret_cast<const bf16x8*>(ks + tid * 8);
            rk[1] = *reinterpret_cast<const bf16x8*>(ks + (tid + 256) * 8);
            { int d = tid >> 3, c8 = tid & 7;
              rv[0] = *reinterpret_cast<const bf16x8*>(vbase + (size_t)d * LK + cbase + 128 + c8 * 8); }
            if (tid < 176) { int c = tid + 256, d = c >> 3, c8 = c & 7;
              rv[1] = *reinterpret_cast<const bf16x8*>(vbase + (size_t)d * LK + cbase + 128 + c8 * 8); }
            if (tid < 64) biasR = bias[b * LK + cbase + 128 + tid];
        }
        const int flag = padflag[b * NT_ + t];

        // S^T = K Q^T (operand-swapped): lane q-row rq, k-pos cbase+nt*16+l4*4+r
        f32x4 S[4];
        #pragma unroll
        for (int nt = 0; nt < 4; ++nt) {
            int krow = nt * 16 + l15, s = (krow & 7) << 3;
            bf16x8 b0 = *reinterpret_cast<const bf16x8*>(&Ks[p][krow * 64 + ((l4 * 8) ^ s)]);
            bf16x8 b1 = *reinterpret_cast<const bf16x8*>(&Ks[p][krow * 64 + ((32 + l4 * 8) ^ s)]);
            f32x4 acc = (f32x4){0.f, 0.f, 0.f, 0.f};
            acc = __builtin_amdgcn_mfma_f32_16x16x32_bf16(b0, aQ[0], acc, 0, 0, 0);
            acc = __builtin_amdgcn_mfma_f32_16x16x32_bf16(b1, aQ[1], acc, 0, 0, 0);
            S[nt] = acc;
        }
        if (flag) {
            #pragma unroll
            for (int nt = 0; nt < 4; ++nt)
                #pragma unroll
                for (int r = 0; r < 4; ++r)
                    S[nt][r] += biasS[p][nt * 16 + l4 * 4 + r];
        }
        if (t == qt + 1) {   // diagonal tile: causal
            #pragma unroll
            for (int nt = 0; nt < 4; ++nt)
                #pragma unroll
                for (int r = 0; r < 4; ++r) {
                    int cg = cbase + nt * 16 + l4 * 4 + r;
                    if (cg > rq + M_) S[nt][r] = -1e30f;
                }
        }
        // softmax for q-row rq (15 in-lane fmax + 2 shfl)
        float mx = fmaxf(fmaxf(S[0][0], S[0][1]), fmaxf(S[0][2], S[0][3]));
        #pragma unroll
        for (int nt = 1; nt < 4; ++nt)
            mx = fmaxf(mx, fmaxf(fmaxf(S[nt][0], S[nt][1]), fmaxf(S[nt][2], S[nt][3])));
        mx = fmaxf(mx, __shfl_xor(mx, 16));
        mx = fmaxf(mx, __shfl_xor(mx, 32));
        float m_new = fmaxf(m_run, mx);
        float alpha = exp2f(m_run - m_new);
        m_run = m_new;
        float ls = 0.f;
        #pragma unroll
        for (int nt = 0; nt < 4; ++nt)
            #pragma unroll
            for (int r = 0; r < 4; ++r) {
                float pv = exp2f(S[nt][r] - m_new);
                S[nt][r] = pv;
                ls += pv;
            }
        ls += __shfl_xor(ls, 16);
        ls += __shfl_xor(ls, 32);
        l_run = l_run * alpha + ls;
        {   // P -> Ps (wave-private strip), b64 packed stores
            int prow = 16 * w + l15, s = (prow & 7) << 3;
            #pragma unroll
            for (int nt = 0; nt < 4; ++nt) {
                bf16x4 pk;
                pk[0] = (__bf16)S[nt][0]; pk[1] = (__bf16)S[nt][1];
                pk[2] = (__bf16)S[nt][2]; pk[3] = (__bf16)S[nt][3];
                *reinterpret_cast<bf16x4*>(&Ps[prow * 64 + ((nt * 16 + l4 * 4) ^ s)]) = pk;
            }
        }
        // alpha to O-row space
        float aO[4];
        #pragma unroll
        for (int r = 0; r < 4; ++r)
            aO[r] = __shfl(alpha, (lane & 0x30) | (l4 * 4 + r), 64);
        #pragma unroll
        for (int nt = 0; nt < 4; ++nt)
            #pragma unroll
            for (int r = 0; r < 4; ++r) Oacc[nt][r] *= aO[r];
        // PV
        bf16x8 aP[2];
        {
            int prow = 16 * w + l15, s = (prow & 7) << 3;
            aP[0] = *reinterpret_cast<const bf16x8*>(&Ps[prow * 64 + ((l4 * 8) ^ s)]);
            aP[1] = *reinterpret_cast<const bf16x8*>(&Ps[prow * 64 + ((32 + l4 * 8) ^ s)]);
        }
        #pragma unroll
        for (int nt = 0; nt < 4; ++nt) {
            int vrow = nt * 16 + l15, s = (vrow & 7) << 3;
            bf16x8 v0 = *reinterpret_cast<const bf16x8*>(&Vs[p][vrow * 64 + ((l4 * 8) ^ s)]);
            bf16x8 v1 = *reinterpret_cast<const bf16x8*>(&Vs[p][vrow * 64 + ((32 + l4 * 8) ^ s)]);
            Oacc[nt] = __builtin_amdgcn_mfma_f32_16x16x32_bf16(aP[0], v0, Oacc[nt], 0, 0, 0);
            Oacc[nt] = __builtin_amdgcn_mfma_f32_16x16x32_bf16(aP[1], v1, Oacc[nt], 0, 0, 0);
        }
        __syncthreads();   // single barrier: reads of buf p + writes of buf p^1 done
        p ^= 1;
    }

    if (l4 == 0) {
        ml[((size_t)pb * 64 + 16 * w + l15) * 2 + 0] = m_run;
        ml[((size_t)pb * 64 + 16 * w + l15) * 2 + 1] = l_run;
    }
    #pragma unroll
    for (int nt = 0; nt < 4; ++nt) {
        int c = nt * 16 + l15;
        if (c < HD) {
            #pragma unroll
            for (int r = 0; r < 4; ++r)
                op[((size_t)pb * HD + c) * 64 + 16 * w + l4 * 4 + r] = Oacc[nt][r];
        }
    }
}

// ---------------------------------------------------------------------------
// combine partials -> aoutb bf16 [8192][256] (R7-verified)
// ---------------------------------------------------------------------------
__global__ __launch_bounds__(256) void combine(const float* __restrict__ op,
                                               const float* __restrict__ ml,
                                               __bf16* __restrict__ aoutb) {
    const int qt = blockIdx.x, bh = blockIdx.y;
    const int b = bh >> 2, h = bh & 3;
    const int ns = (qt + 9) >> 3;
    int accq = 0;
    for (int q = 0; q < qt; ++q) accq += (q + 9) >> 3;
    const int pb0 = bh * SPB + accq;
    const int row = threadIdx.x & 63;
    const int dseg = threadIdx.x >> 6;

    float mi[5], li[5];
    float m = -1e30f;
    for (int i = 0; i < ns; ++i) {
        mi[i] = ml[((size_t)(pb0 + i) * 64 + row) * 2 + 0];
        li[i] = ml[((size_t)(pb0 + i) * 64 + row) * 2 + 1];
        m = fmaxf(m, mi[i]);
    }
    float wgt[5], Lr = 0.f;
    for (int i = 0; i < ns; ++i) {
        wgt[i] = exp2f(mi[i] - m);
        Lr += li[i] * wgt[i];
    }
    float inv = 1.f / Lr;
    #pragma unroll
    for (int j = 0; j < 14; ++j) {
        int d = dseg * 14 + j;
        if (d < HD) {
            float o = 0.f;
            for (int i = 0; i < ns; ++i)
                o += wgt[i] * op[((size_t)(pb0 + i) * HD + d) * 64 + row];
            aoutb[((size_t)(b * L_) + qt * 64 + row) * KP + h * HD + d] = (__bf16)(o * inv);
        }
    }
}

// ---------------------------------------------------------------------------
extern "C" void kernel_launch(void* const* d_in, const int* in_sizes, int n_in,
                              void* d_out, int out_size, void* d_ws, size_t ws_size,
                              hipStream_t stream) {
    const float* x     = (const float*)d_in[0];
    const float* mem_k = (const float*)d_in[1];
    const float* mem_v = (const float*)d_in[2];
    const int*   amask = (const int*)d_in[3];
    const float* Wqkv  = (const float*)d_in[4];
    const float* Wo    = (const float*)d_in[5];
    float* out = (float*)d_out;

    char* p = (char*)d_ws;
    float* bias    = (float*)p;        p += (size_t)B_ * LK * 4;
    int*   padflag = (int*)p;          p += (size_t)B_ * NT_ * 4;
    float2* table  = (float2*)p;       p += (size_t)2048 * 32 * 8;
    __bf16* wqkvt  = (__bf16*)p;       p += (size_t)768 * KP * 2;
    __bf16* wot    = (__bf16*)p;       p += (size_t)256 * KP * 2;
    __bf16* aoutb  = (__bf16*)p;       p += (size_t)8192 * KP * 2;
    __bf16* qb     = (__bf16*)p;       p += (size_t)16 * 2048 * 64 * 2;
    __bf16* kall   = (__bf16*)p;       p += (size_t)16 * 2112 * 64 * 2;
    __bf16* vt     = (__bf16*)p;       p += (size_t)16 * 54 * 2112 * 2;
    float* opbuf   = (float*)p;        p += (size_t)16 * SPB * HD * 64 * 4;  // 18.6MB
    float* mlbuf   = (float*)p;        p += (size_t)16 * SPB * 64 * 2 * 4;

    prep<<<dim3(1570), 256, 0, stream>>>(Wqkv, Wo, amask, mem_k, mem_v,
                                         wqkvt, wot, table, bias, padflag, kall, vt);
    gemm_qkv<<<dim3(12, 64), 256, 0, stream>>>(x, wqkvt, table, qb, kall, vt);
    flash_split<<<dim3(SPB, 16), 256, 0, stream>>>(qb, kall, vt, bias, padflag,
                                                   opbuf, mlbuf);
    combine<<<dim3(32, 16), 256, 0, stream>>>(opbuf, mlbuf, aoutb);
    gemm_out<<<dim3(4, 64), 256, 0, stream>>>(aoutb, wot, out, 216);
}

// Round 10
// 98.538 us; speedup vs baseline: 1.2535x; 1.0216x over previous
//
#include <hip/hip_runtime.h>
#include <math.h>

#define B_ 4
#define L_ 2048
#define D_ 216
#define H_ 4
#define HD 54
#define HDP 64
#define M_ 64
#define LK 2112
#define NT_ 33      // LK/64 col-tiles
#define KP 256      // padded K for MFMA GEMMs
#define SPB 84      // split-blocks per (b,h): sum ceil((qt+2)/8)
#define QSCALE 0.19632593f   // 54^-0.5 * log2(e)

typedef __attribute__((ext_vector_type(8))) __bf16 bf16x8;
typedef __attribute__((ext_vector_type(4))) __bf16 bf16x4;
typedef __attribute__((ext_vector_type(4))) float f32x4;

// packed q/k column -> original d: pc j (0..53) = 2*ii+half -> ii + 27*half
__device__ __forceinline__ int unpack_d(int j) { return (j >> 1) + 27 * (j & 1); }

// ---------------------------------------------------------------------------
// prep: wqkvt (pair-permuted) | wot | sincos table | bias | flags | memkv
// ---------------------------------------------------------------------------
__global__ __launch_bounds__(256) void prep(const float* __restrict__ Wqkv,
                                            const float* __restrict__ Wo,
                                            const int* __restrict__ amask,
                                            const float* __restrict__ mk,
                                            const float* __restrict__ mv,
                                            __bf16* __restrict__ wqkvt,
                                            __bf16* __restrict__ wot,
                                            float2* __restrict__ table,
                                            float* __restrict__ bias,
                                            int* __restrict__ padflag,
                                            __bf16* __restrict__ kall,
                                            __bf16* __restrict__ vt) {
    const int bid = blockIdx.x, tid = threadIdx.x;
    if (bid < 768) {                       // wqkvt [768][256], packed columns
        int idx = bid * 256 + tid;
        int pc = idx >> 8, k = idx & 255;
        float v = 0.f;
        if (k < 216) {
            int col = -1;
            if (pc < 256) { int h = pc >> 6, j = pc & 63;
                if (j < HD) col = h * HD + unpack_d(j); }
            else if (pc < 512) { int h = (pc - 256) >> 6, j = (pc - 256) & 63;
                if (j < HD) col = 216 + h * HD + unpack_d(j); }
            else if (pc < 728) col = 432 + (pc - 512);
            if (col >= 0) v = Wqkv[(size_t)k * 648 + col];
        }
        wqkvt[idx] = (__bf16)v;
    } else if (bid < 1024) {               // wot [256][256]
        int idx = (bid - 768) * 256 + tid;
        int n = idx >> 8, k = idx & 255;
        wot[idx] = (__bf16)((n < 216 && k < 216) ? Wo[(size_t)k * 216 + n] : 0.f);
    } else if (bid < 1280) {               // sincos table [2048][32] float2
        int idx = (bid - 1024) * 256 + tid;
        int l = idx >> 5, ii = idx & 31;
        float2 sc = {0.f, 0.f};
        if (ii < 27) {
            float ang = (float)l * exp2f(-0.49213749924f * (float)ii);
            sc.x = sinf(ang); sc.y = cosf(ang);
        }
        table[idx] = sc;
    } else if (bid < 1313) {               // bias [B][LK]
        int idx = (bid - 1280) * 256 + tid;
        if (idx < B_ * LK) {
            int b = idx / LK, c = idx % LK;
            bias[idx] = (c < M_ || amask[b * L_ + c - M_] != 0) ? 0.f : -1e30f;
        }
    } else if (bid == 1313) {              // pad_flags [B][33]
        if (tid < B_ * NT_) {
            int b = tid / NT_, tile = tid % NT_;
            int flag = 0;
            for (int u = 0; u < 64; ++u) {
                int c = tile * 64 + u;
                if (c >= M_ && c < LK && amask[b * L_ + c - M_] == 0) flag = 1;
            }
            padflag[tid] = flag;
        }
    } else {                               // memkv (packed-d for K, natural for V)
        int idx = (bid - 1314) * 256 + tid;   // 65536
        int b  = idx >> 14;
        int m  = (idx >> 8) & 63;
        int h  = (idx >> 6) & 3;
        int dd = idx & 63;
        float kv = (dd < HD) ? mk[((size_t)(b * M_ + m)) * D_ + h * HD + unpack_d(dd)] : 0.f;
        kall[((size_t)(b * 4 + h) * LK + m) * HDP + dd] = (__bf16)kv;
        if (dd < HD)
            vt[((size_t)(b * 4 + h) * HD + dd) * LK + m] =
                (__bf16)mv[((size_t)(b * M_ + m)) * D_ + h * HD + dd];
    }
}

// ---------------------------------------------------------------------------
// Fused QKV GEMM + RoPE epilogue (R7-verified).
// ---------------------------------------------------------------------------
__global__ __launch_bounds__(256) void gemm_qkv(const float* __restrict__ x,
                                                const __bf16* __restrict__ Bt,
                                                const float2* __restrict__ table,
                                                __bf16* __restrict__ qb,
                                                __bf16* __restrict__ kall,
                                                __bf16* __restrict__ vt) {
    __shared__ __align__(16) __bf16 As[8192];   // [128][64] swizzled
    __shared__ __align__(16) __bf16 Bs[4096];   // [64][64] swizzled
    const int col0 = blockIdx.x * 64;
    const int row0 = blockIdx.y * 128;
    const int tid = threadIdx.x;
    const int lane = tid & 63;
    const int w = tid >> 6, wm = w >> 1, wn = w & 1;
    const int l15 = lane & 15, l4 = lane >> 4;

    f32x4 acc[4][2];
    #pragma unroll
    for (int m = 0; m < 4; ++m)
        #pragma unroll
        for (int n = 0; n < 2; ++n) acc[m][n] = (f32x4){0.f, 0.f, 0.f, 0.f};

    float4 rfa[4][2];
    bf16x8 rb[2];
    #pragma unroll
    for (int i = 0; i < 4; ++i) { int c = tid + 256 * i, r = c >> 3, c8 = c & 7;
        int k = c8 * 8;
        rfa[i][0] = *reinterpret_cast<const float4*>(x + (size_t)(row0 + r) * 216 + k);
        rfa[i][1] = *reinterpret_cast<const float4*>(x + (size_t)(row0 + r) * 216 + k + 4); }
    #pragma unroll
    for (int i = 0; i < 2; ++i) { int c = tid + 256 * i, r = c >> 3, c8 = c & 7;
        rb[i] = *reinterpret_cast<const bf16x8*>(Bt + (size_t)(col0 + r) * KP + c8 * 8); }

    for (int kit = 0; kit < 4; ++kit) {
        __syncthreads();
        #pragma unroll
        for (int i = 0; i < 4; ++i) { int c = tid + 256 * i, r = c >> 3, c8 = c & 7;
            bf16x8 v;
            #pragma unroll
            for (int j = 0; j < 4; ++j) { v[j] = (__bf16)rfa[i][0][j]; v[4 + j] = (__bf16)rfa[i][1][j]; }
            *reinterpret_cast<bf16x8*>(&As[r * 64 + ((c8 ^ (r & 7)) * 8)]) = v; }
        #pragma unroll
        for (int i = 0; i < 2; ++i) { int c = tid + 256 * i, r = c >> 3, c8 = c & 7;
            *reinterpret_cast<bf16x8*>(&Bs[r * 64 + ((c8 ^ (r & 7)) * 8)]) = rb[i]; }
        __syncthreads();
        if (kit < 3) {
            const int k0 = (kit + 1) * 64;
            #pragma unroll
            for (int i = 0; i < 4; ++i) { int c = tid + 256 * i, r = c >> 3, c8 = c & 7;
                int k = k0 + c8 * 8;
                if (k < 216) {
                    rfa[i][0] = *reinterpret_cast<const float4*>(x + (size_t)(row0 + r) * 216 + k);
                    rfa[i][1] = *reinterpret_cast<const float4*>(x + (size_t)(row0 + r) * 216 + k + 4);
                } else {
                    rfa[i][0] = (float4){0.f, 0.f, 0.f, 0.f};
                    rfa[i][1] = (float4){0.f, 0.f, 0.f, 0.f};
                } }
            #pragma unroll
            for (int i = 0; i < 2; ++i) { int c = tid + 256 * i, r = c >> 3, c8 = c & 7;
                rb[i] = *reinterpret_cast<const bf16x8*>(Bt + (size_t)(col0 + r) * KP + k0 + c8 * 8); }
        }
        #pragma unroll
        for (int ks = 0; ks < 2; ++ks) {
            bf16x8 af[4], bfr[2];
            #pragma unroll
            for (int m = 0; m < 4; ++m) { int row = wm * 64 + m * 16 + l15; int ch = ks * 4 + l4;
                af[m] = *reinterpret_cast<const bf16x8*>(&As[row * 64 + ((ch ^ (row & 7)) * 8)]); }
            #pragma unroll
            for (int n = 0; n < 2; ++n) { int row = wn * 32 + n * 16 + l15; int ch = ks * 4 + l4;
                bfr[n] = *reinterpret_cast<const bf16x8*>(&Bs[row * 64 + ((ch ^ (row & 7)) * 8)]); }
            #pragma unroll
            for (int m = 0; m < 4; ++m)
                #pragma unroll
                for (int n = 0; n < 2; ++n)
                    acc[m][n] = __builtin_amdgcn_mfma_f32_16x16x32_bf16(af[m], bfr[n], acc[m][n], 0, 0, 0);
        }
    }

    // ---- fused RoPE epilogue ----
    #pragma unroll
    for (int m = 0; m < 4; ++m)
        #pragma unroll
        for (int n = 0; n < 2; ++n) {
            const int cc = col0 + wn * 32 + n * 16 + l15;
            const int rowb = row0 + wm * 64 + m * 16 + l4 * 4;
            const int b = rowb >> 11;
            const int lbase = rowb & 2047;
            if (cc < 512) {                     // q (cc<256) or k region, packed
                const bool isq = cc < 256;
                const int h = (cc >> 6) & 3, j = cc & 63;
                const int half = j & 1, ii = j >> 1;   // table padded to 32
                #pragma unroll
                for (int rr = 0; rr < 4; ++rr) {
                    float me = acc[m][n][rr];
                    float pr = __shfl_xor(me, 1);
                    float2 sc = table[(lbase + rr) * 32 + ii];
                    float v = me * sc.y + (half ? pr * sc.x : -pr * sc.x);
                    if (isq) {
                        qb[((size_t)(b * 4 + h) * L_ + lbase + rr) * HDP + j] =
                            (__bf16)(v * QSCALE);
                    } else {
                        kall[((size_t)(b * 4 + h) * LK + M_ + lbase + rr) * HDP + j] =
                            (__bf16)v;
                    }
                }
            } else if (cc < 728) {              // v region, natural order, transpose
                const int dp = cc - 512;
                const int h = (dp * 1214) >> 16;     // dp/54
                const int d = dp - h * 54;
                #pragma unroll
                for (int rr = 0; rr < 4; ++rr)
                    vt[((size_t)(b * 4 + h) * HD + d) * LK + M_ + lbase + rr] =
                        (__bf16)acc[m][n][rr];
            }
        }
}

// ---------------------------------------------------------------------------
// bf16 MFMA GEMM (R4-verified): C[8192][N] fp32 = A[8192][256] @ Bt[256][256]^T
// ---------------------------------------------------------------------------
__global__ __launch_bounds__(256) void gemm_out(const __bf16* __restrict__ A,
                                                const __bf16* __restrict__ Bt,
                                                float* __restrict__ C, int N) {
    __shared__ __align__(16) __bf16 As[8192];
    __shared__ __align__(16) __bf16 Bs[4096];
    const int col0 = blockIdx.x * 64;
    const int row0 = blockIdx.y * 128;
    const int tid = threadIdx.x;
    const int lane = tid & 63;
    const int w = tid >> 6, wm = w >> 1, wn = w & 1;
    const int l15 = lane & 15, l4 = lane >> 4;

    f32x4 acc[4][2];
    #pragma unroll
    for (int m = 0; m < 4; ++m)
        #pragma unroll
        for (int n = 0; n < 2; ++n) acc[m][n] = (f32x4){0.f, 0.f, 0.f, 0.f};

    bf16x8 ra[4], rb[2];
    #pragma unroll
    for (int i = 0; i < 4; ++i) { int c = tid + 256 * i, r = c >> 3, c8 = c & 7;
        ra[i] = *reinterpret_cast<const bf16x8*>(A + (size_t)(row0 + r) * KP + c8 * 8); }
    #pragma unroll
    for (int i = 0; i < 2; ++i) { int c = tid + 256 * i, r = c >> 3, c8 = c & 7;
        rb[i] = *reinterpret_cast<const bf16x8*>(Bt + (size_t)(col0 + r) * KP + c8 * 8); }

    for (int kit = 0; kit < 4; ++kit) {
        __syncthreads();
        #pragma unroll
        for (int i = 0; i < 4; ++i) { int c = tid + 256 * i, r = c >> 3, c8 = c & 7;
            *reinterpret_cast<bf16x8*>(&As[r * 64 + ((c8 ^ (r & 7)) * 8)]) = ra[i]; }
        #pragma unroll
        for (int i = 0; i < 2; ++i) { int c = tid + 256 * i, r = c >> 3, c8 = c & 7;
            *reinterpret_cast<bf16x8*>(&Bs[r * 64 + ((c8 ^ (r & 7)) * 8)]) = rb[i]; }
        __syncthreads();
        if (kit < 3) {
            const int k0 = (kit + 1) * 64;
            #pragma unroll
            for (int i = 0; i < 4; ++i) { int c = tid + 256 * i, r = c >> 3, c8 = c & 7;
                ra[i] = *reinterpret_cast<const bf16x8*>(A + (size_t)(row0 + r) * KP + k0 + c8 * 8); }
            #pragma unroll
            for (int i = 0; i < 2; ++i) { int c = tid + 256 * i, r = c >> 3, c8 = c & 7;
                rb[i] = *reinterpret_cast<const bf16x8*>(Bt + (size_t)(col0 + r) * KP + k0 + c8 * 8); }
        }
        #pragma unroll
        for (int ks = 0; ks < 2; ++ks) {
            bf16x8 af[4], bfr[2];
            #pragma unroll
            for (int m = 0; m < 4; ++m) { int row = wm * 64 + m * 16 + l15; int ch = ks * 4 + l4;
                af[m] = *reinterpret_cast<const bf16x8*>(&As[row * 64 + ((ch ^ (row & 7)) * 8)]); }
            #pragma unroll
            for (int n = 0; n < 2; ++n) { int row = wn * 32 + n * 16 + l15; int ch = ks * 4 + l4;
                bfr[n] = *reinterpret_cast<const bf16x8*>(&Bs[row * 64 + ((ch ^ (row & 7)) * 8)]); }
            #pragma unroll
            for (int m = 0; m < 4; ++m)
                #pragma unroll
                for (int n = 0; n < 2; ++n)
                    acc[m][n] = __builtin_amdgcn_mfma_f32_16x16x32_bf16(af[m], bfr[n], acc[m][n], 0, 0, 0);
        }
    }
    #pragma unroll
    for (int m = 0; m < 4; ++m)
        #pragma unroll
        for (int n = 0; n < 2; ++n) {
            int cc = col0 + wn * 32 + n * 16 + l15;
            if (cc < N) {
                #pragma unroll
                for (int rr = 0; rr < 4; ++rr)
                    C[(size_t)(row0 + wm * 64 + m * 16 + l4 * 4 + rr) * N + cc] = acc[m][n][rr];
            }
        }
}

// ---------------------------------------------------------------------------
// flash split-K, dbuf (R9) + swapped PV (O^T accumulator, alpha lane-local)
// + defer-max (THR=8 in log2 domain).  op[pb][54][64] + ml[pb][64][2].
// ---------------------------------------------------------------------------
__global__ __launch_bounds__(256) void flash_split(const __bf16* __restrict__ qb,
                                                   const __bf16* __restrict__ kall,
                                                   const __bf16* __restrict__ vt,
                                                   const float* __restrict__ bias,
                                                   const int* __restrict__ padflag,
                                                   float* __restrict__ op,
                                                   float* __restrict__ ml) {
    int qt = 31, sp = 0;
    {
        int sidx = blockIdx.x, accq = 0;
        for (int q = 0; q < 32; ++q) {
            int c = (q + 9) >> 3;   // ceil((q+2)/8)
            if (sidx < accq + c) { qt = q; sp = sidx - accq; break; }
            accq += c;
        }
    }
    const int pb = blockIdx.y * SPB + blockIdx.x;
    const int q0 = qt * 64;
    const int bh = blockIdx.y;
    const int b = bh >> 2;
    const int tstart = sp * 8;
    const int tend = min(tstart + 8, qt + 2);

    __shared__ __align__(16) __bf16 Qs[4096];
    __shared__ __align__(16) __bf16 Ks[2][4096];
    __shared__ __align__(16) __bf16 Vs[2][4096];
    __shared__ __align__(16) __bf16 Ps[4096];
    __shared__ float biasS[2][64];

    const int tid = threadIdx.x;
    const int lane = tid & 63;
    const int w = tid >> 6;
    const int l15 = lane & 15;
    const int l4 = lane >> 4;

    {   // stage Q (swizzled) + zero V pad rows in BOTH buffers
        const __bf16* src = qb + ((size_t)bh * L_ + q0) * HDP;
        for (int ch = tid; ch < 512; ch += 256) {
            int row = ch >> 3, c8 = ch & 7;
            bf16x8 v = *reinterpret_cast<const bf16x8*>(src + ch * 8);
            *reinterpret_cast<bf16x8*>(&Qs[row * 64 + ((c8 ^ (row & 7)) * 8)]) = v;
        }
        if (tid < 160) {
            int buf = tid >= 80, q = tid - 80 * buf;
            int d = 54 + (q >> 3), c8 = q & 7;
            bf16x8 z{};
            *reinterpret_cast<bf16x8*>(&Vs[buf][d * 64 + ((c8 ^ (d & 7)) * 8)]) = z;
        }
    }

    const int rq = q0 + 16 * w + l15;
    const __bf16* kbase = kall + (size_t)bh * LK * HDP;
    const __bf16* vbase = vt + (size_t)bh * HD * LK;

    bf16x8 rk[2], rv[2];
    float biasR = 0.f;
    {   // tile tstart: load regs and commit straight to buf 0
        const __bf16* ks = kbase + (size_t)tstart * 64 * HDP;
        rk[0] = *reinterpret_cast<const bf16x8*>(ks + tid * 8);
        rk[1] = *reinterpret_cast<const bf16x8*>(ks + (tid + 256) * 8);
        { int d = tid >> 3, c8 = tid & 7;
          rv[0] = *reinterpret_cast<const bf16x8*>(vbase + (size_t)d * LK + tstart * 64 + c8 * 8); }
        if (tid < 176) { int c = tid + 256, d = c >> 3, c8 = c & 7;
          rv[1] = *reinterpret_cast<const bf16x8*>(vbase + (size_t)d * LK + tstart * 64 + c8 * 8); }
        if (tid < 64) biasR = bias[b * LK + tstart * 64 + tid];

        { int r = tid >> 3, c8 = tid & 7;
          *reinterpret_cast<bf16x8*>(&Ks[0][r * 64 + ((c8 ^ (r & 7)) * 8)]) = rk[0]; }
        { int c = tid + 256, r = c >> 3, c8 = c & 7;
          *reinterpret_cast<bf16x8*>(&Ks[0][r * 64 + ((c8 ^ (r & 7)) * 8)]) = rk[1]; }
        { int d = tid >> 3, c8 = tid & 7;
          *reinterpret_cast<bf16x8*>(&Vs[0][d * 64 + ((c8 ^ (d & 7)) * 8)]) = rv[0]; }
        if (tid < 176) { int c = tid + 256, d = c >> 3, c8 = c & 7;
          *reinterpret_cast<bf16x8*>(&Vs[0][d * 64 + ((c8 ^ (d & 7)) * 8)]) = rv[1]; }
        if (tid < 64) biasS[0][tid] = biasR;
    }
    if (tstart + 1 < tend) {   // prefetch tile tstart+1 into regs
        const __bf16* ks = kbase + (size_t)(tstart + 1) * 64 * HDP;
        rk[0] = *reinterpret_cast<const bf16x8*>(ks + tid * 8);
        rk[1] = *reinterpret_cast<const bf16x8*>(ks + (tid + 256) * 8);
        { int d = tid >> 3, c8 = tid & 7;
          rv[0] = *reinterpret_cast<const bf16x8*>(vbase + (size_t)d * LK + (tstart + 1) * 64 + c8 * 8); }
        if (tid < 176) { int c = tid + 256, d = c >> 3, c8 = c & 7;
          rv[1] = *reinterpret_cast<const bf16x8*>(vbase + (size_t)d * LK + (tstart + 1) * 64 + c8 * 8); }
        if (tid < 64) biasR = bias[b * LK + (tstart + 1) * 64 + tid];
    }

    __syncthreads();   // Q, buf0, V-pads all visible
    bf16x8 aQ[2];
    {
        int qrow = 16 * w + l15, s = (qrow & 7) << 3;
        aQ[0] = *reinterpret_cast<const bf16x8*>(&Qs[qrow * 64 + ((l4 * 8) ^ s)]);
        aQ[1] = *reinterpret_cast<const bf16x8*>(&Qs[qrow * 64 + ((32 + l4 * 8) ^ s)]);
    }

    // O^T accumulator: Oacc[nt][r] = O^T[d = nt*16+l4*4+r][q = l15 (of 16w+l15)]
    f32x4 Oacc[4];
    #pragma unroll
    for (int nt = 0; nt < 4; ++nt) Oacc[nt] = (f32x4){0.f, 0.f, 0.f, 0.f};
    float m_run = -1e30f, l_run = 0.f;

    int p = 0;
    for (int t = tstart; t < tend; ++t) {
        const int cbase = t * 64;
        const int qbuf = p ^ 1;
        if (t + 1 < tend) {   // commit staged regs (tile t+1) to other buffer
            { int r = tid >> 3, c8 = tid & 7;
              *reinterpret_cast<bf16x8*>(&Ks[qbuf][r * 64 + ((c8 ^ (r & 7)) * 8)]) = rk[0]; }
            { int c = tid + 256, r = c >> 3, c8 = c & 7;
              *reinterpret_cast<bf16x8*>(&Ks[qbuf][r * 64 + ((c8 ^ (r & 7)) * 8)]) = rk[1]; }
            { int d = tid >> 3, c8 = tid & 7;
              *reinterpret_cast<bf16x8*>(&Vs[qbuf][d * 64 + ((c8 ^ (d & 7)) * 8)]) = rv[0]; }
            if (tid < 176) { int c = tid + 256, d = c >> 3, c8 = c & 7;
              *reinterpret_cast<bf16x8*>(&Vs[qbuf][d * 64 + ((c8 ^ (d & 7)) * 8)]) = rv[1]; }
            if (tid < 64) biasS[qbuf][tid] = biasR;
        }
        if (t + 2 < tend) {   // issue tile t+2 global loads (in flight over compute)
            const __bf16* ks = kbase + (size_t)(cbase + 128) * HDP;
            rk[0] = *reinterpret_cast<const bf16x8*>(ks + tid * 8);
            rk[1] = *reinterpret_cast<const bf16x8*>(ks + (tid + 256) * 8);
            { int d = tid >> 3, c8 = tid & 7;
              rv[0] = *reinterpret_cast<const bf16x8*>(vbase + (size_t)d * LK + cbase + 128 + c8 * 8); }
            if (tid < 176) { int c = tid + 256, d = c >> 3, c8 = c & 7;
              rv[1] = *reinterpret_cast<const bf16x8*>(vbase + (size_t)d * LK + cbase + 128 + c8 * 8); }
            if (tid < 64) biasR = bias[b * LK + cbase + 128 + tid];
        }
        const int flag = padflag[b * NT_ + t];

        // S^T = K Q^T (operand-swapped): lane q-row rq, k-pos cbase+nt*16+l4*4+r
        f32x4 S[4];
        #pragma unroll
        for (int nt = 0; nt < 4; ++nt) {
            int krow = nt * 16 + l15, s = (krow & 7) << 3;
            bf16x8 b0 = *reinterpret_cast<const bf16x8*>(&Ks[p][krow * 64 + ((l4 * 8) ^ s)]);
            bf16x8 b1 = *reinterpret_cast<const bf16x8*>(&Ks[p][krow * 64 + ((32 + l4 * 8) ^ s)]);
            f32x4 acc = (f32x4){0.f, 0.f, 0.f, 0.f};
            acc = __builtin_amdgcn_mfma_f32_16x16x32_bf16(b0, aQ[0], acc, 0, 0, 0);
            acc = __builtin_amdgcn_mfma_f32_16x16x32_bf16(b1, aQ[1], acc, 0, 0, 0);
            S[nt] = acc;
        }
        if (flag) {
            #pragma unroll
            for (int nt = 0; nt < 4; ++nt)
                #pragma unroll
                for (int r = 0; r < 4; ++r)
                    S[nt][r] += biasS[p][nt * 16 + l4 * 4 + r];
        }
        if (t == qt + 1) {   // diagonal tile: causal
            #pragma unroll
            for (int nt = 0; nt < 4; ++nt)
                #pragma unroll
                for (int r = 0; r < 4; ++r) {
                    int cg = cbase + nt * 16 + l4 * 4 + r;
                    if (cg > rq + M_) S[nt][r] = -1e30f;
                }
        }
        // row max (max3-friendly tree) + 2 shfl
        float mx;
        {
            float a0 = fmaxf(fmaxf(S[0][0], S[0][1]), S[0][2]);
            float a1 = fmaxf(fmaxf(S[0][3], S[1][0]), S[1][1]);
            float a2 = fmaxf(fmaxf(S[1][2], S[1][3]), S[2][0]);
            float a3 = fmaxf(fmaxf(S[2][1], S[2][2]), S[2][3]);
            float a4 = fmaxf(fmaxf(S[3][0], S[3][1]), S[3][2]);
            float b0 = fmaxf(fmaxf(a0, a1), a2);
            float b1 = fmaxf(fmaxf(a3, a4), S[3][3]);
            mx = fmaxf(b0, b1);
        }
        mx = fmaxf(mx, __shfl_xor(mx, 16));
        mx = fmaxf(mx, __shfl_xor(mx, 32));
        // defer-max: skip rescale when tile max is within THR of running max
        if (!__all(mx <= m_run + 8.f)) {
            float m_new = fmaxf(m_run, mx);
            float alpha = exp2f(m_run - m_new);
            m_run = m_new;
            l_run *= alpha;
            #pragma unroll
            for (int nt = 0; nt < 4; ++nt)
                #pragma unroll
                for (int r = 0; r < 4; ++r) Oacc[nt][r] *= alpha;   // lane-local (O^T)
        }
        float ls = 0.f;
        #pragma unroll
        for (int nt = 0; nt < 4; ++nt)
            #pragma unroll
            for (int r = 0; r < 4; ++r) {
                float pv = exp2f(S[nt][r] - m_run);
                S[nt][r] = pv;
                ls += pv;
            }
        ls += __shfl_xor(ls, 16);
        ls += __shfl_xor(ls, 32);
        l_run += ls;
        {   // P -> Ps (wave-private strip), b64 packed stores
            int prow = 16 * w + l15, s = (prow & 7) << 3;
            #pragma unroll
            for (int nt = 0; nt < 4; ++nt) {
                bf16x4 pk;
                pk[0] = (__bf16)S[nt][0]; pk[1] = (__bf16)S[nt][1];
                pk[2] = (__bf16)S[nt][2]; pk[3] = (__bf16)S[nt][3];
                *reinterpret_cast<bf16x4*>(&Ps[prow * 64 + ((nt * 16 + l4 * 4) ^ s)]) = pk;
            }
        }
        // PV swapped: O^T = mfma(V-frag, P-frag) — alpha already applied lane-local
        bf16x8 aP[2];
        {
            int prow = 16 * w + l15, s = (prow & 7) << 3;
            aP[0] = *reinterpret_cast<const bf16x8*>(&Ps[prow * 64 + ((l4 * 8) ^ s)]);
            aP[1] = *reinterpret_cast<const bf16x8*>(&Ps[prow * 64 + ((32 + l4 * 8) ^ s)]);
        }
        #pragma unroll
        for (int nt = 0; nt < 4; ++nt) {
            int vrow = nt * 16 + l15, s = (vrow & 7) << 3;
            bf16x8 v0 = *reinterpret_cast<const bf16x8*>(&Vs[p][vrow * 64 + ((l4 * 8) ^ s)]);
            bf16x8 v1 = *reinterpret_cast<const bf16x8*>(&Vs[p][vrow * 64 + ((32 + l4 * 8) ^ s)]);
            Oacc[nt] = __builtin_amdgcn_mfma_f32_16x16x32_bf16(v0, aP[0], Oacc[nt], 0, 0, 0);
            Oacc[nt] = __builtin_amdgcn_mfma_f32_16x16x32_bf16(v1, aP[1], Oacc[nt], 0, 0, 0);
        }
        __syncthreads();   // single barrier: reads of buf p + writes of buf p^1 done
        p ^= 1;
    }

    // emit partials: ml lane-local (q = 16w+l15), O^T store d = nt*16+l4*4+r
    if (l4 == 0) {
        ml[((size_t)pb * 64 + 16 * w + l15) * 2 + 0] = m_run;
        ml[((size_t)pb * 64 + 16 * w + l15) * 2 + 1] = l_run;
    }
    #pragma unroll
    for (int nt = 0; nt < 4; ++nt) {
        #pragma unroll
        for (int r = 0; r < 4; ++r) {
            int d = nt * 16 + l4 * 4 + r;
            if (d < HD)
                op[((size_t)pb * HD + d) * 64 + 16 * w + l15] = Oacc[nt][r];
        }
    }
}

// ---------------------------------------------------------------------------
// combine partials -> aoutb bf16 [8192][256] (R7-verified)
// ---------------------------------------------------------------------------
__global__ __launch_bounds__(256) void combine(const float* __restrict__ op,
                                               const float* __restrict__ ml,
                                               __bf16* __restrict__ aoutb) {
    const int qt = blockIdx.x, bh = blockIdx.y;
    const int b = bh >> 2, h = bh & 3;
    const int ns = (qt + 9) >> 3;
    int accq = 0;
    for (int q = 0; q < qt; ++q) accq += (q + 9) >> 3;
    const int pb0 = bh * SPB + accq;
    const int row = threadIdx.x & 63;
    const int dseg = threadIdx.x >> 6;

    float mi[5], li[5];
    float m = -1e30f;
    for (int i = 0; i < ns; ++i) {
        mi[i] = ml[((size_t)(pb0 + i) * 64 + row) * 2 + 0];
        li[i] = ml[((size_t)(pb0 + i) * 64 + row) * 2 + 1];
        m = fmaxf(m, mi[i]);
    }
    float wgt[5], Lr = 0.f;
    for (int i = 0; i < ns; ++i) {
        wgt[i] = exp2f(mi[i] - m);
        Lr += li[i] * wgt[i];
    }
    float inv = 1.f / Lr;
    #pragma unroll
    for (int j = 0; j < 14; ++j) {
        int d = dseg * 14 + j;
        if (d < HD) {
            float o = 0.f;
            for (int i = 0; i < ns; ++i)
                o += wgt[i] * op[((size_t)(pb0 + i) * HD + d) * 64 + row];
            aoutb[((size_t)(b * L_) + qt * 64 + row) * KP + h * HD + d] = (__bf16)(o * inv);
        }
    }
}

// ---------------------------------------------------------------------------
extern "C" void kernel_launch(void* const* d_in, const int* in_sizes, int n_in,
                              void* d_out, int out_size, void* d_ws, size_t ws_size,
                              hipStream_t stream) {
    const float* x     = (const float*)d_in[0];
    const float* mem_k = (const float*)d_in[1];
    const float* mem_v = (const float*)d_in[2];
    const int*   amask = (const int*)d_in[3];
    const float* Wqkv  = (const float*)d_in[4];
    const float* Wo    = (const float*)d_in[5];
    float* out = (float*)d_out;

    char* p = (char*)d_ws;
    float* bias    = (float*)p;        p += (size_t)B_ * LK * 4;
    int*   padflag = (int*)p;          p += (size_t)B_ * NT_ * 4;
    float2* table  = (float2*)p;       p += (size_t)2048 * 32 * 8;
    __bf16* wqkvt  = (__bf16*)p;       p += (size_t)768 * KP * 2;
    __bf16* wot    = (__bf16*)p;       p += (size_t)256 * KP * 2;
    __bf16* aoutb  = (__bf16*)p;       p += (size_t)8192 * KP * 2;
    __bf16* qb     = (__bf16*)p;       p += (size_t)16 * 2048 * 64 * 2;
    __bf16* kall   = (__bf16*)p;       p += (size_t)16 * 2112 * 64 * 2;
    __bf16* vt     = (__bf16*)p;       p += (size_t)16 * 54 * 2112 * 2;
    float* opbuf   = (float*)p;        p += (size_t)16 * SPB * HD * 64 * 4;  // 18.6MB
    float* mlbuf   = (float*)p;        p += (size_t)16 * SPB * 64 * 2 * 4;

    prep<<<dim3(1570), 256, 0, stream>>>(Wqkv, Wo, amask, mem_k, mem_v,
                                         wqkvt, wot, table, bias, padflag, kall, vt);
    gemm_qkv<<<dim3(12, 64), 256, 0, stream>>>(x, wqkvt, table, qb, kall, vt);
    flash_split<<<dim3(SPB, 16), 256, 0, stream>>>(qb, kall, vt, bias, padflag,
                                                   opbuf, mlbuf);
    combine<<<dim3(32, 16), 256, 0, stream>>>(opbuf, mlbuf, aoutb);
    gemm_out<<<dim3(4, 64), 256, 0, stream>>>(aoutb, wot, out, 216);
}